// Round 4
// baseline (4340.719 us; speedup 1.0000x reference)
//
#include <hip/hip_runtime.h>
#include <hip/hip_bf16.h>
#include <math.h>

static constexpr int Bx = 4, Sx = 1024, Dx = 1024, NHx = 16, DHx = 64;
static constexpr int FFx = 4096, NEx = 8, OUTx = 1024, BSx = Bx * Sx;

__device__ __forceinline__ void ld4f(const float* p, float* o) {
    float4 v = *(const float4*)p;
    o[0] = v.x; o[1] = v.y; o[2] = v.z; o[3] = v.w;
}

// diagnostic: report ws_size (MB) through the absmax channel
__global__ __launch_bounds__(256) void diag_k(float* __restrict__ out, int n, float val)
{
    int i = blockIdx.x * 256 + threadIdx.x;
    if (i < n) out[i] = val;
}

// ---------------------------------------------------------------------------
// fp32 GEMM: C[M,N] = A[M,K] @ B[K,N] (+bias[N]) (opt relu)
// 64x64 tile, BK=16, 256 threads, 4x4 microtile/thread.
// ---------------------------------------------------------------------------
template<int RELU>
__global__ __launch_bounds__(256) void gemm_k(const float* __restrict__ A,
        const float* __restrict__ B, const float* __restrict__ bias,
        float* __restrict__ C, int M, int N, int K)
{
    __shared__ __align__(16) float As[16][64];
    __shared__ __align__(16) float Bs[16][64];
    const int tid = threadIdx.x;
    const int tx = tid & 15, ty = tid >> 4;
    const int m0 = blockIdx.y * 64, n0 = blockIdx.x * 64;
    float acc[4][4];
#pragma unroll
    for (int i = 0; i < 4; i++)
#pragma unroll
        for (int j = 0; j < 4; j++) acc[i][j] = 0.f;

    const int ma = tid >> 2, ka = (tid & 3) * 4;   // A-tile load coords
    const int kb = tid >> 4, nb = (tid & 15) * 4;  // B-tile load coords

    for (int k0 = 0; k0 < K; k0 += 16) {
        const float* ap = A + (size_t)(m0 + ma) * K + k0 + ka;
#pragma unroll
        for (int i = 0; i < 4; i++) As[ka + i][ma] = ap[i];
        const float* bp = B + (size_t)(k0 + kb) * N + n0 + nb;
#pragma unroll
        for (int i = 0; i < 4; i++) Bs[kb][nb + i] = bp[i];
        __syncthreads();
#pragma unroll
        for (int k = 0; k < 16; k++) {
            float a[4], bb[4];
            ld4f(&As[k][ty * 4], a);
            ld4f(&Bs[k][tx * 4], bb);
#pragma unroll
            for (int i = 0; i < 4; i++)
#pragma unroll
                for (int j = 0; j < 4; j++)
                    acc[i][j] = fmaf(a[i], bb[j], acc[i][j]);
        }
        __syncthreads();
    }
#pragma unroll
    for (int i = 0; i < 4; i++) {
        int m = m0 + ty * 4 + i;
#pragma unroll
        for (int j = 0; j < 4; j++) {
            int n = n0 + tx * 4 + j;
            float v = acc[i][j];
            if (bias) v += bias[n];
            if (RELU) v = fmaxf(v, 0.f);
            C[(size_t)m * N + n] = v;
        }
    }
}

// ---------------------------------------------------------------------------
// Sinusoidal relative position embedding pe[S,D], positions S-1..0.
// Double precision internally: fp32 angle rounding at arg~1000 is a 1e-4
// perturbation -> router flips downstream.
// ---------------------------------------------------------------------------
__global__ __launch_bounds__(256) void pe_k(float* __restrict__ pe)
{
    int idx = blockIdx.x * 256 + threadIdx.x;  // over Sx*512
    int s = idx >> 9, j = idx & 511;
    double pos = (double)(Sx - 1 - s);
    double invf = exp(-((double)(2 * j) / (double)Dx) * log(10000.0));
    double ang = pos * invf;
    pe[(size_t)s * Dx + j]       = (float)sin(ang);
    pe[(size_t)s * Dx + 512 + j] = (float)cos(ang);
}

// ---------------------------------------------------------------------------
// Flash-style causal attention with TransformerXL relative bias, all fp32.
// bd[q,k] = (q+v_bias) . r[S-1-(q-k)]  (causal region k<=q)
// Tile: 64 q x 32 k. LDS: Qs 16K + KP(K/P union) 8K + Vs 8K + RBT 24K = 56.5K
// ---------------------------------------------------------------------------
__global__ __launch_bounds__(256) void attn_k(const float* __restrict__ qkv,
        const float* __restrict__ r, const float* __restrict__ u_bias,
        const float* __restrict__ v_bias, float* __restrict__ ctx)
{
    const int qt = blockIdx.x;          // q tile 0..15
    const int bh = blockIdx.y;          // 0..63
    const int b = bh >> 4, h = bh & 15;
    const int q0 = qt * 64;
    const int tid = threadIdx.x;
    const int tx = tid & 15, ty = tid >> 4;

    __shared__ __align__(16) float Qs[64][64];   // [d][q] raw q
    __shared__ __align__(16) float KP[2048];     // KT[d][k]=KP[d*32+k] / PT[k][q]=KP[k*64+q]
    __shared__ __align__(16) float Vs[32][64];   // [k][d]
    __shared__ __align__(16) float RBT[64][96];  // [d][t], delta = q0-k0+t-31
    __shared__ float us[64], vs[64];

    for (int e = tid; e < 64 * 64; e += 256) {
        int qi = e >> 6, d = e & 63;
        Qs[d][qi] = qkv[((size_t)(b * Sx + q0 + qi)) * (3 * Dx) + h * DHx + d];
    }
    if (tid < 64) { us[tid] = u_bias[h * DHx + tid]; vs[tid] = v_bias[h * DHx + tid]; }

    float m_st[4], l_st[4], O[4][4];
#pragma unroll
    for (int i = 0; i < 4; i++) {
        m_st[i] = -1e30f; l_st[i] = 0.f;
#pragma unroll
        for (int j = 0; j < 4; j++) O[i][j] = 0.f;
    }

    const int nkt = 2 * qt + 2;
    for (int kt = 0; kt < nkt; kt++) {
        const int k0 = kt * 32;
        __syncthreads();  // prev PV reads of KP/Vs/RBT done before overwrite
        for (int e = tid; e < 32 * 64; e += 256) {
            int ki = e >> 6, d = e & 63;
            size_t base = ((size_t)(b * Sx + k0 + ki)) * (3 * Dx) + h * DHx + d;
            KP[d * 32 + ki] = qkv[base + Dx];
            Vs[ki][d]       = qkv[base + 2 * Dx];
        }
        for (int e = tid; e < 64 * 96; e += 256) {
            int d = e / 96, t = e - 96 * d;
            int delta = q0 - k0 + t - 31;
            float val = 0.f;
            if (t < 95 && delta >= 0 && delta < Sx)
                val = r[(size_t)(Sx - 1 - delta) * Dx + h * DHx + d];
            RBT[d][t] = val;
        }
        __syncthreads();

        float sc[4][2];
#pragma unroll
        for (int i = 0; i < 4; i++) { sc[i][0] = 0.f; sc[i][1] = 0.f; }

        // ac + bd fused over d: sc += (q+u).k + (q+v).r_rev
        const int tb = 4 * ty - 2 * tx + 31;   // t = tb + i - j, in [0,94]
#pragma unroll 4
        for (int d = 0; d < 64; d++) {
            float a[4];
            ld4f(&Qs[d][ty * 4], a);
            float k0v = KP[d * 32 + 2 * tx], k1v = KP[d * 32 + 2 * tx + 1];
            float uu = us[d], vv = vs[d];
            float rb[5];
#pragma unroll
            for (int t = 0; t < 5; t++) rb[t] = RBT[d][tb - 1 + t];
#pragma unroll
            for (int i = 0; i < 4; i++) {
                float qu = a[i] + uu, qv = a[i] + vv;
                sc[i][0] = fmaf(qu, k0v, fmaf(qv, rb[i + 1], sc[i][0]));
                sc[i][1] = fmaf(qu, k1v, fmaf(qv, rb[i],     sc[i][1]));
            }
        }

        // scale, causal mask, online softmax (rows distributed over tx:16 lanes x 2 cols)
#pragma unroll
        for (int i = 0; i < 4; i++) {
            int qg = q0 + 4 * ty + i;
#pragma unroll
            for (int j = 0; j < 2; j++) {
                sc[i][j] *= 0.125f;
                if ((k0 + 2 * tx + j) > qg) sc[i][j] = -1e30f;
            }
            float mx = fmaxf(sc[i][0], sc[i][1]);
#pragma unroll
            for (int off = 8; off > 0; off >>= 1) mx = fmaxf(mx, __shfl_xor(mx, off, 16));
            float mnew = fmaxf(m_st[i], mx);
            float alpha = __expf(m_st[i] - mnew);
            m_st[i] = mnew;
            float rs = 0.f;
#pragma unroll
            for (int j = 0; j < 2; j++) { sc[i][j] = __expf(sc[i][j] - mnew); rs += sc[i][j]; }
#pragma unroll
            for (int off = 8; off > 0; off >>= 1) rs += __shfl_xor(rs, off, 16);
            l_st[i] = l_st[i] * alpha + rs;
#pragma unroll
            for (int j = 0; j < 4; j++) O[i][j] *= alpha;
        }

        __syncthreads();  // all KT reads done before PT overwrites KP
#pragma unroll
        for (int i = 0; i < 4; i++)
#pragma unroll
            for (int j = 0; j < 2; j++)
                KP[(2 * tx + j) * 64 + 4 * ty + i] = sc[i][j];   // PT[k][q]
        __syncthreads();
#pragma unroll 4
        for (int ki = 0; ki < 32; ki++) {
            float p[4], vv[4];
            ld4f(&KP[ki * 64 + ty * 4], p);
            ld4f(&Vs[ki][tx * 4], vv);
#pragma unroll
            for (int i = 0; i < 4; i++)
#pragma unroll
                for (int j = 0; j < 4; j++)
                    O[i][j] = fmaf(p[i], vv[j], O[i][j]);
        }
    }
#pragma unroll
    for (int i = 0; i < 4; i++) {
        float inv = (l_st[i] > 0.f) ? 1.f / l_st[i] : 0.f;
#pragma unroll
        for (int j = 0; j < 4; j++)
            ctx[((size_t)(b * Sx + q0 + ty * 4 + i)) * Dx + h * DHx + tx * 4 + j]
                = O[i][j] * inv;
    }
}

// ---------------------------------------------------------------------------
// LayerNorm: out = LN(resid + add) * g + b  (one row per block, fp32)
// In-place safe (each thread reads exactly the elements it writes).
// ---------------------------------------------------------------------------
__global__ __launch_bounds__(256) void ln_k(const float* __restrict__ resid,
        const float* __restrict__ add, const float* __restrict__ g,
        const float* __restrict__ b, float* __restrict__ out)
{
    const int row = blockIdx.x, tid = threadIdx.x;
    const float* rr = resid + (size_t)row * Dx;
    const float* ar = add + (size_t)row * Dx;
    float v[4], s = 0.f, sq = 0.f;
#pragma unroll
    for (int i = 0; i < 4; i++) {
        int d = tid + i * 256;
        v[i] = rr[d] + ar[d];
        s += v[i]; sq += v[i] * v[i];
    }
#pragma unroll
    for (int off = 32; off > 0; off >>= 1) {
        s  += __shfl_down(s, off, 64);
        sq += __shfl_down(sq, off, 64);
    }
    __shared__ float red[8];
    int w = tid >> 6;
    if ((tid & 63) == 0) { red[w] = s; red[4 + w] = sq; }
    __syncthreads();
    s  = red[0] + red[1] + red[2] + red[3];
    sq = red[4] + red[5] + red[6] + red[7];
    float mean = s * (1.f / Dx);
    float var = fmaxf(sq * (1.f / Dx) - mean * mean, 0.f);
    float rstd = rsqrtf(var + 1e-5f);
#pragma unroll
    for (int i = 0; i < 4; i++) {
        int d = tid + i * 256;
        out[(size_t)row * Dx + d] = (v[i] - mean) * rstd * g[d] + b[d];
    }
}

// ---------------------------------------------------------------------------
// MoE routing: top-1 argmax (first-max-wins, numpy semantics) +
// gate = 1/sum(exp(l-lmax)); builds expert token lists.
// ---------------------------------------------------------------------------
__global__ __launch_bounds__(64) void route_k(const float* __restrict__ h,
        const float* __restrict__ Wg, float* __restrict__ gate,
        int* __restrict__ counts, int* __restrict__ lists)
{
    const int t = blockIdx.x, lane = threadIdx.x;
    float part[NEx];
#pragma unroll
    for (int e = 0; e < NEx; e++) part[e] = 0.f;
    const float* hr = h + (size_t)t * Dx;
    for (int d = lane; d < Dx; d += 64) {
        float hv = hr[d];
        const float* wr = Wg + (size_t)d * NEx;
#pragma unroll
        for (int e = 0; e < NEx; e++) part[e] = fmaf(hv, wr[e], part[e]);
    }
#pragma unroll
    for (int e = 0; e < NEx; e++)
#pragma unroll
        for (int off = 32; off > 0; off >>= 1)
            part[e] += __shfl_down(part[e], off, 64);
    if (lane == 0) {
        float mx = part[0]; int am = 0;
#pragma unroll
        for (int e = 1; e < NEx; e++) if (part[e] > mx) { mx = part[e]; am = e; }
        float ssum = 0.f;
#pragma unroll
        for (int e = 0; e < NEx; e++) ssum += expf(part[e] - mx);
        gate[t] = 1.f / ssum;
        int pos = atomicAdd(&counts[am], 1);
        lists[am * BSx + pos] = t;
    }
}

__global__ void zero_counts_k(int* counts) { if (threadIdx.x < NEx) counts[threadIdx.x] = 0; }

// ---------------------------------------------------------------------------
// Grouped MoE GEMM (gather by expert token list, scatter result), fp32.
// PASS 1: hid = relu(h @ We1[e] + be1[e]);  PASS 2: (hid@We2[e]+be2[e])*gate
// ---------------------------------------------------------------------------
template<int PASS>
__global__ __launch_bounds__(256) void moe_gemm_k(const float* __restrict__ Act,
        const float* __restrict__ W, const float* __restrict__ bias,
        const int* __restrict__ lists, const int* __restrict__ counts,
        const float* __restrict__ gate, float* __restrict__ Out, int N, int K)
{
    const int e = blockIdx.z;
    const int cnt = counts[e];
    const int t0 = blockIdx.y * 64;
    if (t0 >= cnt) return;
    const int tid = threadIdx.x;
    const int tx = tid & 15, ty = tid >> 4;
    const int n0 = blockIdx.x * 64;

    __shared__ int toks[64];
    __shared__ __align__(16) float As[16][64];
    __shared__ __align__(16) float Bs[16][64];
    if (tid < 64) toks[tid] = (t0 + tid < cnt) ? lists[e * BSx + t0 + tid] : -1;
    __syncthreads();

    const float* We = W + (size_t)e * K * N;
    float acc[4][4];
#pragma unroll
    for (int i = 0; i < 4; i++)
#pragma unroll
        for (int j = 0; j < 4; j++) acc[i][j] = 0.f;

    const int ma = tid >> 2, ka = (tid & 3) * 4;
    const int kb = tid >> 4, nb = (tid & 15) * 4;

    for (int k0 = 0; k0 < K; k0 += 16) {
        int tok = toks[ma];
#pragma unroll
        for (int i = 0; i < 4; i++)
            As[ka + i][ma] = (tok >= 0) ? Act[(size_t)tok * K + k0 + ka + i] : 0.f;
        const float* bp = We + (size_t)(k0 + kb) * N + n0 + nb;
#pragma unroll
        for (int i = 0; i < 4; i++) Bs[kb][nb + i] = bp[i];
        __syncthreads();
#pragma unroll
        for (int k = 0; k < 16; k++) {
            float a[4], bb[4];
            ld4f(&As[k][ty * 4], a);
            ld4f(&Bs[k][tx * 4], bb);
#pragma unroll
            for (int i = 0; i < 4; i++)
#pragma unroll
                for (int j = 0; j < 4; j++)
                    acc[i][j] = fmaf(a[i], bb[j], acc[i][j]);
        }
        __syncthreads();
    }
#pragma unroll
    for (int i = 0; i < 4; i++) {
        int tok = toks[ty * 4 + i];
        if (tok < 0) continue;
#pragma unroll
        for (int j = 0; j < 4; j++) {
            int n = n0 + tx * 4 + j;
            float v = acc[i][j] + bias[(size_t)e * N + n];
            if (PASS == 1) Out[(size_t)tok * N + n] = fmaxf(v, 0.f);
            else           Out[(size_t)tok * N + n] = v * gate[tok];
        }
    }
}

// ---------------------------------------------------------------------------
extern "C" void kernel_launch(void* const* d_in, const int* in_sizes, int n_in,
                              void* d_out, int out_size, void* d_ws, size_t ws_size,
                              hipStream_t stream)
{
    (void)in_sizes; (void)n_in;
    const float* x      = (const float*)d_in[0];
    const float* Wqkv   = (const float*)d_in[1];
    const float* Wo     = (const float*)d_in[2];
    const float* Wr     = (const float*)d_in[3];
    const float* u_bias = (const float*)d_in[4];
    const float* v_bias = (const float*)d_in[5];
    const float* ln1_g  = (const float*)d_in[6];
    const float* ln1_b  = (const float*)d_in[7];
    const float* Wff1   = (const float*)d_in[8];
    const float* bff1   = (const float*)d_in[9];
    const float* Wff2   = (const float*)d_in[10];
    const float* bff2   = (const float*)d_in[11];
    const float* ln2_g  = (const float*)d_in[12];
    const float* ln2_b  = (const float*)d_in[13];
    const float* Wg     = (const float*)d_in[14];
    const float* We1    = (const float*)d_in[15];
    const float* be1    = (const float*)d_in[16];
    const float* We2    = (const float*)d_in[17];
    const float* be2    = (const float*)d_in[18];
    const float* ln3_g  = (const float*)d_in[19];
    const float* ln3_b  = (const float*)d_in[20];
    const float* Wout   = (const float*)d_in[21];
    float* out = (float*)d_out;

    // ---- fp32 workspace overlay (~109.2 MB peak) ----
    char* base = (char*)d_ws;
    const size_t QKV_B = (size_t)BSx * 3 * Dx * 4;        // 50,331,648
    const size_t PE_B  = (size_t)Sx * Dx * 4;             //  4,194,304
    const size_t CTX_B = (size_t)BSx * Dx * 4;            // 16,777,216
    const size_t P2    = QKV_B + 2 * PE_B + CTX_B;        // 75,497,472
    const size_t NEEDED = P2 + 2 * CTX_B + 16384 + 256 + (size_t)NEx * BSx * 4;

    if (ws_size < NEEDED) {  // report ws_size (MB) through the absmax channel
        diag_k<<<(out_size + 255) / 256, 256, 0, stream>>>(out, out_size,
                                                           (float)(ws_size >> 20));
        return;
    }

    float* qkv  = (float*)(base);                          // phase 1
    float* pe   = (float*)(base + QKV_B);
    float* rbuf = (float*)(base + QKV_B + PE_B);
    float* ctx  = (float*)(base + QKV_B + 2 * PE_B);
    float* ffh  = (float*)(base);                          // phase 2 overlay (64 MB < 72 MB)
    float* tmp  = (float*)(base + P2);
    float* h    = (float*)(base + P2 + CTX_B);             // h1 -> h2 -> h3 in place
    float* gate = (float*)(base + P2 + 2 * CTX_B);
    int* counts = (int*)(base + P2 + 2 * CTX_B + 16384);
    int* lists  = (int*)(base + P2 + 2 * CTX_B + 16384 + 256);

    // 1. qkv = x @ Wqkv
    gemm_k<0><<<dim3(3 * Dx / 64, BSx / 64), 256, 0, stream>>>(
        x, Wqkv, nullptr, qkv, BSx, 3 * Dx, Dx);
    // 2. pe (double-precision sinusoid) ; r = pe @ Wr
    pe_k<<<Sx * 512 / 256, 256, 0, stream>>>(pe);
    gemm_k<0><<<dim3(Dx / 64, Sx / 64), 256, 0, stream>>>(
        pe, Wr, nullptr, rbuf, Sx, Dx, Dx);
    // 3. attention
    attn_k<<<dim3(Sx / 64, Bx * NHx), 256, 0, stream>>>(qkv, rbuf, u_bias, v_bias, ctx);
    // 4. h = LN(x + ctx @ Wo)
    gemm_k<0><<<dim3(Dx / 64, BSx / 64), 256, 0, stream>>>(
        ctx, Wo, nullptr, tmp, BSx, Dx, Dx);
    ln_k<<<BSx, 256, 0, stream>>>(x, tmp, ln1_g, ln1_b, h);
    // 5. FFN: h = LN(h + relu(h@Wff1+b)@Wff2+b)   (ffh overlays dead phase-1 region)
    gemm_k<1><<<dim3(FFx / 64, BSx / 64), 256, 0, stream>>>(
        h, Wff1, bff1, ffh, BSx, FFx, Dx);
    gemm_k<0><<<dim3(Dx / 64, BSx / 64), 256, 0, stream>>>(
        ffh, Wff2, bff2, tmp, BSx, Dx, FFx);
    ln_k<<<BSx, 256, 0, stream>>>(h, tmp, ln2_g, ln2_b, h);
    // 6. MoE top-1 routing + grouped expert FFN
    zero_counts_k<<<1, 64, 0, stream>>>(counts);
    route_k<<<BSx, 64, 0, stream>>>(h, Wg, gate, counts, lists);
    moe_gemm_k<1><<<dim3(FFx / 64, BSx / 64, NEx), 256, 0, stream>>>(
        h, We1, be1, lists, counts, gate, ffh, FFx, Dx);
    moe_gemm_k<2><<<dim3(Dx / 64, BSx / 64, NEx), 256, 0, stream>>>(
        ffh, We2, be2, lists, counts, gate, tmp, Dx, FFx);
    // 7. h = LN(h + moe)
    ln_k<<<BSx, 256, 0, stream>>>(h, tmp, ln3_g, ln3_b, h);
    // 8. out = h @ Wout
    gemm_k<0><<<dim3(OUTx / 64, BSx / 64), 256, 0, stream>>>(
        h, Wout, nullptr, out, BSx, OUTx, Dx);
}